// Round 2
// 773.172 us; speedup vs baseline: 1.0282x; 1.0282x over previous
//
#include <hip/hip_runtime.h>
#include <math.h>

// NNUE forward, all f32 in/out. B=8192, N_IN=12288, H0=256, H1=H2=32.
// R10: R9 with the nontemporal-load type fixed — __builtin_nontemporal_load
//     rejects HIP_vector_type<uint,4>; use clang ext_vector_type(4) instead
//     (lowers to global_load_dwordx4 ... nt).
//     Theory: the 805 MB zero-reuse scan stream evicts the 6.3 MB bf16
//     table from L2 (4 MiB/XCD) and LLC (inputs ~819 MB > 256 MB), so the
//     ~260 MB of gather traffic partially misses to HBM. `nt` loads make
//     the stream evict-first, keeping tab cache-resident.
//     Predicted: nnue_mono FETCH_SIZE -15..25%, total dur 795 -> ~720-760.
// Measured machine limits: fills (write) 6.5 TB/s; copy 6.29 TB/s (r+w).
//     Harness fixed overhead ~550 us (poison fills, not controllable).

#define NIN   12288
#define NF4   3072   // NIN / 4 floats per float4
#define H0    256
#define MAXF  192    // per-sample active-feature cap (mean ~31)

typedef unsigned int uintx4 __attribute__((ext_vector_type(4)));

__device__ __forceinline__ float bflo(unsigned u) { return __uint_as_float(u << 16); }
__device__ __forceinline__ float bfhi(unsigned u) { return __uint_as_float(u & 0xFFFF0000u); }

// ---------------------------------------------------------------- transpose
// ft_w (256 x 12288) f32 -> ft_w_T (12288 x 256) bf16 (RNE), LDS-tiled.
__global__ __launch_bounds__(256) void transpose_ftw_bf16(const float* __restrict__ src,
                                                          unsigned short* __restrict__ dst) {
    __shared__ float tile[32][33];
    const int jb = blockIdx.x * 32;
    const int hb = blockIdx.y * 32;
    const int tx = threadIdx.x;
    const int ty = threadIdx.y;
#pragma unroll
    for (int r = 0; r < 32; r += 8)
        tile[ty + r][tx] = src[(size_t)(hb + ty + r) * NIN + jb + tx];
    __syncthreads();
#pragma unroll
    for (int r = 0; r < 32; r += 8) {
        const unsigned u = __float_as_uint(tile[tx][ty + r]);
        const unsigned short h = (unsigned short)((u + 0x7FFFu + ((u >> 16) & 1u)) >> 16);
        dst[(size_t)(jb + ty + r) * H0 + hb + tx] = h;
    }
}

// ---------------------------------------------------------------- monolith
__global__ __launch_bounds__(256) void nnue_mono(
    const float* __restrict__ white,        // (B, NIN)
    const float* __restrict__ black,
    const int* __restrict__ side,           // (B,)
    const unsigned* __restrict__ tab,       // (NIN,128) uints = (NIN,256) bf16
    const float* __restrict__ ft_b,         // (256,)
    const float* __restrict__ l1_w,         // (32,512)
    const float* __restrict__ l1_b,
    const float* __restrict__ l2_w,         // (32,32)
    const float* __restrict__ l2_b,
    const float* __restrict__ l3_w,         // (32,)
    const float* __restrict__ l3_b,         // (1,)
    float* __restrict__ out)                // (B,)
{
    __shared__ int w_list[MAXF];
    __shared__ int b_list[MAXF];
    __shared__ int w_cnt, b_cnt;
    __shared__ float sh_o0[512] __attribute__((aligned(16)));
    __shared__ float sh_o1[32];
    __shared__ float sh_o2[32];

    const int s   = blockIdx.x;
    const int tid = threadIdx.x;

    if (tid == 0) { w_cnt = 0; b_cnt = 0; }
    __syncthreads();

    // ---- Phase 1: stream both feature rows (24 uint4/thread), collect ----
    // Non-temporal: zero-reuse stream, keep it OUT of L2/LLC so tab stays
    // resident for Phase 2's gathers.
    const uintx4* wrow = (const uintx4*)(white + (size_t)s * NIN);
    const uintx4* brow = (const uintx4*)(black + (size_t)s * NIN);
#pragma unroll
    for (int i = 0; i < 3; ++i) {
        uintx4 w4[4], b4[4];
#pragma unroll
        for (int k = 0; k < 4; ++k) w4[k] = __builtin_nontemporal_load(&wrow[(i * 4 + k) * 256 + tid]);
#pragma unroll
        for (int k = 0; k < 4; ++k) b4[k] = __builtin_nontemporal_load(&brow[(i * 4 + k) * 256 + tid]);
#pragma unroll
        for (int k = 0; k < 4; ++k) {
            const int v = (i * 4 + k) * 256 + tid;
            const uintx4 u = w4[k];
            if (u.x | u.y | u.z | u.w) {
                if (u.x) { int p = atomicAdd(&w_cnt, 1); if (p < MAXF) w_list[p] = v * 4 + 0; }
                if (u.y) { int p = atomicAdd(&w_cnt, 1); if (p < MAXF) w_list[p] = v * 4 + 1; }
                if (u.z) { int p = atomicAdd(&w_cnt, 1); if (p < MAXF) w_list[p] = v * 4 + 2; }
                if (u.w) { int p = atomicAdd(&w_cnt, 1); if (p < MAXF) w_list[p] = v * 4 + 3; }
            }
            const uintx4 b = b4[k];
            if (b.x | b.y | b.z | b.w) {
                if (b.x) { int p = atomicAdd(&b_cnt, 1); if (p < MAXF) b_list[p] = v * 4 + 0; }
                if (b.y) { int p = atomicAdd(&b_cnt, 1); if (p < MAXF) b_list[p] = v * 4 + 1; }
                if (b.z) { int p = atomicAdd(&b_cnt, 1); if (p < MAXF) b_list[p] = v * 4 + 2; }
                if (b.w) { int p = atomicAdd(&b_cnt, 1); if (p < MAXF) b_list[p] = v * 4 + 3; }
            }
        }
    }
    __syncthreads();

    const int wn = min(w_cnt, MAXF);
    const int bn = min(b_cnt, MAXF);

    // ---- Phase 2: bf16 gather; tid<128: white units (2h,2h+1); else black ----
    const int  h       = tid & 127;
    const bool isWhite = (tid < 128);
    const int* lst     = isWhite ? w_list : b_list;
    const int  n       = isWhite ? wn : bn;
    const unsigned* colp = tab + h;

    float accx = ft_b[2 * h];
    float accy = ft_b[2 * h + 1];
    {
        int k = 0;
        for (; k + 8 <= n; k += 8) {
            const unsigned u0 = colp[(size_t)lst[k]     * 128];
            const unsigned u1 = colp[(size_t)lst[k + 1] * 128];
            const unsigned u2 = colp[(size_t)lst[k + 2] * 128];
            const unsigned u3 = colp[(size_t)lst[k + 3] * 128];
            const unsigned u4 = colp[(size_t)lst[k + 4] * 128];
            const unsigned u5 = colp[(size_t)lst[k + 5] * 128];
            const unsigned u6 = colp[(size_t)lst[k + 6] * 128];
            const unsigned u7 = colp[(size_t)lst[k + 7] * 128];
            accx += ((bflo(u0) + bflo(u1)) + (bflo(u2) + bflo(u3))) +
                    ((bflo(u4) + bflo(u5)) + (bflo(u6) + bflo(u7)));
            accy += ((bfhi(u0) + bfhi(u1)) + (bfhi(u2) + bfhi(u3))) +
                    ((bfhi(u4) + bfhi(u5)) + (bfhi(u6) + bfhi(u7)));
        }
        for (; k < n; ++k) {
            const unsigned u = colp[(size_t)lst[k] * 128];
            accx += bflo(u);
            accy += bfhi(u);
        }
    }
    const float cx = fminf(fmaxf(accx, 0.f), 1.f);
    const float cy = fminf(fmaxf(accy, 0.f), 1.f);
    const bool sd = (side[s] != 0);
    const int base = (isWhite == sd) ? 0 : 256;   // white -> first half iff side
    sh_o0[base + 2 * h]     = cx;
    sh_o0[base + 2 * h + 1] = cy;
    __syncthreads();

    // ---- l1: (32,512); 8 threads/output, p-staggered (bank-conflict-free) ----
    {
        const int o = tid >> 3;
        const int p = tid & 7;
        const float4* wp = (const float4*)(l1_w + (o * 512 + p * 64));
        const float4* xp = (const float4*)(sh_o0 + p * 64);
        float sum = 0.f;
#pragma unroll
        for (int i = 0; i < 16; ++i) {
            const int v = (2 * p + i) & 15;
            float4 w4 = wp[v];
            float4 x4 = xp[v];
            sum += w4.x * x4.x + w4.y * x4.y + w4.z * x4.z + w4.w * x4.w;
        }
        sum += __shfl_down(sum, 4, 8);
        sum += __shfl_down(sum, 2, 8);
        sum += __shfl_down(sum, 1, 8);
        if (p == 0) sh_o1[o] = fminf(fmaxf(sum + l1_b[o], 0.f), 1.f);
    }
    __syncthreads();

    if (tid < 32) {
        float sum = 0.f;
#pragma unroll
        for (int k = 0; k < 32; ++k) sum += l2_w[tid * 32 + k] * sh_o1[k];
        sh_o2[tid] = fminf(fmaxf(sum + l2_b[tid], 0.f), 1.f);
    }
    __syncthreads();

    if (tid < 32) {
        float p = l3_w[tid] * sh_o2[tid];
        p += __shfl_down(p, 16, 32);
        p += __shfl_down(p, 8, 32);
        p += __shfl_down(p, 4, 32);
        p += __shfl_down(p, 2, 32);
        p += __shfl_down(p, 1, 32);
        if (tid == 0) {
            const float o3 = (p + l3_b[0]) * 300.0f;
            out[s] = 1.0f / (1.0f + expf(-o3 / 200.0f));
        }
    }
}

// ---------------------------------------------------------------- fallback (f32, untransposed)
__global__ __launch_bounds__(256) void nnue_kernel(
    const float* __restrict__ white, const float* __restrict__ black,
    const int* __restrict__ side, const float* __restrict__ ftw,
    const float* __restrict__ ft_b, const float* __restrict__ l1_w,
    const float* __restrict__ l1_b, const float* __restrict__ l2_w,
    const float* __restrict__ l2_b, const float* __restrict__ l3_w,
    const float* __restrict__ l3_b, float* __restrict__ out)
{
    __shared__ int w_list[MAXF];
    __shared__ int b_list[MAXF];
    __shared__ int w_cnt, b_cnt;
    __shared__ float sh_o0[512] __attribute__((aligned(16)));
    __shared__ float sh_o1[32];
    __shared__ float sh_o2[32];
    const int s = blockIdx.x, tid = threadIdx.x;
    if (tid == 0) { w_cnt = 0; b_cnt = 0; }
    __syncthreads();
    const uintx4* wrow = (const uintx4*)(white + (size_t)s * NIN);
    const uintx4* brow = (const uintx4*)(black + (size_t)s * NIN);
#pragma unroll
    for (int i = 0; i < 12; ++i) {
        const int v = i * 256 + tid;
        uintx4 u = __builtin_nontemporal_load(&wrow[v]);
        if (u.x | u.y | u.z | u.w) {
            if (u.x) { int p = atomicAdd(&w_cnt, 1); if (p < MAXF) w_list[p] = v * 4 + 0; }
            if (u.y) { int p = atomicAdd(&w_cnt, 1); if (p < MAXF) w_list[p] = v * 4 + 1; }
            if (u.z) { int p = atomicAdd(&w_cnt, 1); if (p < MAXF) w_list[p] = v * 4 + 2; }
            if (u.w) { int p = atomicAdd(&w_cnt, 1); if (p < MAXF) w_list[p] = v * 4 + 3; }
        }
        uintx4 b = __builtin_nontemporal_load(&brow[v]);
        if (b.x | b.y | b.z | b.w) {
            if (b.x) { int p = atomicAdd(&b_cnt, 1); if (p < MAXF) b_list[p] = v * 4 + 0; }
            if (b.y) { int p = atomicAdd(&b_cnt, 1); if (p < MAXF) b_list[p] = v * 4 + 1; }
            if (b.z) { int p = atomicAdd(&b_cnt, 1); if (p < MAXF) b_list[p] = v * 4 + 2; }
            if (b.w) { int p = atomicAdd(&b_cnt, 1); if (p < MAXF) b_list[p] = v * 4 + 3; }
        }
    }
    __syncthreads();
    const int wn = min(w_cnt, MAXF), bn = min(b_cnt, MAXF);
    const float bias = ft_b[tid];
    float wacc = bias, bacc = bias;
    for (int k = 0; k < wn; ++k) wacc += ftw[(size_t)tid * NIN + w_list[k]];
    for (int k = 0; k < bn; ++k) bacc += ftw[(size_t)tid * NIN + b_list[k]];
    const float ow = fminf(fmaxf(wacc, 0.f), 1.f);
    const float ob = fminf(fmaxf(bacc, 0.f), 1.f);
    const bool sd = (side[s] != 0);
    sh_o0[tid] = sd ? ow : ob;
    sh_o0[256 + tid] = sd ? ob : ow;
    __syncthreads();
    {
        const int o = tid >> 3, p = tid & 7;
        const float4* wp = (const float4*)(l1_w + (o * 512 + p * 64));
        const float4* xp = (const float4*)(sh_o0 + p * 64);
        float sum = 0.f;
#pragma unroll
        for (int i = 0; i < 16; ++i) {
            const int v = (2 * p + i) & 15;
            float4 w4 = wp[v]; float4 x4 = xp[v];
            sum += w4.x * x4.x + w4.y * x4.y + w4.z * x4.z + w4.w * x4.w;
        }
        sum += __shfl_down(sum, 4, 8);
        sum += __shfl_down(sum, 2, 8);
        sum += __shfl_down(sum, 1, 8);
        if (p == 0) sh_o1[o] = fminf(fmaxf(sum + l1_b[o], 0.f), 1.f);
    }
    __syncthreads();
    if (tid < 32) {
        float sum = 0.f;
#pragma unroll
        for (int k = 0; k < 32; ++k) sum += l2_w[tid * 32 + k] * sh_o1[k];
        sh_o2[tid] = fminf(fmaxf(sum + l2_b[tid], 0.f), 1.f);
    }
    __syncthreads();
    if (tid < 32) {
        float p = l3_w[tid] * sh_o2[tid];
        p += __shfl_down(p, 16, 32);
        p += __shfl_down(p, 8, 32);
        p += __shfl_down(p, 4, 32);
        p += __shfl_down(p, 2, 32);
        p += __shfl_down(p, 1, 32);
        if (tid == 0) {
            const float o3 = (p + l3_b[0]) * 300.0f;
            out[s] = 1.0f / (1.0f + expf(-o3 / 200.0f));
        }
    }
}

// ---------------------------------------------------------------- launch
extern "C" void kernel_launch(void* const* d_in, const int* in_sizes, int n_in,
                              void* d_out, int out_size, void* d_ws, size_t ws_size,
                              hipStream_t stream) {
    const float* white = (const float*)d_in[0];
    const float* black = (const float*)d_in[1];
    const int*   side  = (const int*)d_in[2];
    const float* ft_w  = (const float*)d_in[3];
    const float* ft_b  = (const float*)d_in[4];
    const float* l1_w  = (const float*)d_in[5];
    const float* l1_b  = (const float*)d_in[6];
    const float* l2_w  = (const float*)d_in[7];
    const float* l2_b  = (const float*)d_in[8];
    const float* l3_w  = (const float*)d_in[9];
    const float* l3_b  = (const float*)d_in[10];
    float*       out   = (float*)d_out;

    const int B = in_sizes[2];
    const size_t t_bytes = (size_t)NIN * H0 * 2;   // bf16 ftw_t: 6.29 MB

    if (ws_size >= t_bytes) {
        unsigned short* ftw_t = (unsigned short*)d_ws;
        hipLaunchKernelGGL(transpose_ftw_bf16, dim3(NIN / 32, H0 / 32), dim3(32, 8), 0, stream,
                           ft_w, ftw_t);
        hipLaunchKernelGGL(nnue_mono, dim3(B), dim3(256), 0, stream,
                           white, black, side, (const unsigned*)ftw_t, ft_b,
                           l1_w, l1_b, l2_w, l2_b, l3_w, l3_b, out);
    } else {
        hipLaunchKernelGGL(nnue_kernel, dim3(B), dim3(256), 0, stream,
                           white, black, side, ft_w, ft_b, l1_w, l1_b, l2_w, l2_b,
                           l3_w, l3_b, out);
    }
}